// Round 3
// baseline (493.944 us; speedup 1.0000x reference)
//
#include <hip/hip_runtime.h>

#define NN 50000
#define EE 640000
#define DINv 64
#define GBv 128
#define GDv 4
#define LBv 256
#define LDv 2
#define GGv 1024

#define NB 196       // coarse buckets (256 nodes each)
#define BCAP 4096    // bucket capacity
#define BTILE 4096   // edges per k_bucket block
#define NBT ((EE + BTILE - 1) / BTILE)  // 157

#define NTILES ((NN + 63) / 64)  // 782 row-tiles
#define UPN (NN * 16)            // uprep float4 groups
#define CONVN (DINv * GBv + GDv * GBv * GBv)
#define ZEXT 320                 // sentinel-row zero elements (64 + 128 + 128)

typedef _Float16 f16x8 __attribute__((ext_vector_type(8)));
typedef float f32x4 __attribute__((ext_vector_type(4)));

__device__ __forceinline__ float h2f(ushort u) {
  union { ushort u; _Float16 h; } x;
  x.u = u;
  return (float)x.h;
}
__device__ __forceinline__ ushort f2h(float f) {
  union { ushort u; _Float16 h; } x;
  x.h = (_Float16)f;
  return x.u;
}

// ---------------- stage 1: coarse bucket sort (dst>>8) ----------------

__global__ __launch_bounds__(256) void k_bucket(const int* __restrict__ ei,
                                                int* __restrict__ bcnt,
                                                uint* __restrict__ bkt) {
  __shared__ int lcnt[NB];
  __shared__ int lbase[NB];
  __shared__ int gbase[NB];
  __shared__ int ls[256];
  __shared__ uint stage[BTILE];
  __shared__ ushort sb[BTILE];
  int tid = threadIdx.x;
  int t0 = blockIdx.x * BTILE;
  int cnt = min(BTILE, EE - t0);
  for (int i = tid; i < NB; i += 256) lcnt[i] = 0;
  __syncthreads();

  uint en[16];
  int bb[16], rk[16];
  int nper = (cnt + 255) >> 8;
  for (int k = 0; k < nper; k++) {
    int e = k * 256 + tid;
    if (e < cnt) {
      int src = ei[t0 + e];
      int dst = ei[EE + t0 + e];
      int b = dst >> 8;
      en[k] = ((uint)src << 8) | (uint)(dst & 255);
      bb[k] = b;
      rk[k] = atomicAdd(&lcnt[b], 1);
    } else {
      bb[k] = -1;
    }
  }
  __syncthreads();

  int v = (tid < NB) ? lcnt[tid] : 0;
  ls[tid] = v;
  __syncthreads();
  for (int off = 1; off < 256; off <<= 1) {
    int t = (tid >= off) ? ls[tid - off] : 0;
    __syncthreads();
    ls[tid] += t;
    __syncthreads();
  }
  if (tid < NB) {
    lbase[tid] = ls[tid] - v;
    gbase[tid] = atomicAdd(&bcnt[tid], v);
  }
  __syncthreads();

  for (int k = 0; k < nper; k++) {
    if (bb[k] >= 0) {
      int slot = lbase[bb[k]] + rk[k];
      stage[slot] = en[k];
      sb[slot] = (ushort)bb[k];
    }
  }
  __syncthreads();

  for (int i = tid; i < cnt; i += 256) {
    int b = sb[i];
    bkt[(size_t)b * BCAP + gbase[b] + (i - lbase[b])] = stage[i];
  }
}

// ---------------- stage 2: per-bucket fine CSR (8-padded with sentinel NN) ----------
// Each node's col segment is padded to a multiple of 8 with sentinel index NN (a zero
// row with dinv[NN]=0) -> branchless 8-wide gather with aligned int4 col loads, zero
// wasted bandwidth (sentinel row is cache-hot). deg[] stores the raw (uncapped) degree.

__global__ __launch_bounds__(256) void k_csr(const uint* __restrict__ bkt,
                                             const int* __restrict__ bcnt,
                                             int* __restrict__ offs,
                                             float* __restrict__ dinv,
                                             int* __restrict__ col,
                                             int* __restrict__ deg,
                                             int* __restrict__ ghist) {
  __shared__ int lhist[256];
  __shared__ int lofs[256];
  __shared__ int lcur[256];
  __shared__ int lsb[256];
  __shared__ int lh2[64];
  int b = blockIdx.x;
  int tid = threadIdx.x;
  int bv = (tid < NB) ? bcnt[tid] : 0;
  lsb[tid] = bv;
  lhist[tid] = 0;
  if (tid < 64) lh2[tid] = 0;
  __syncthreads();
  for (int off = 1; off < 256; off <<= 1) {
    int t = (tid >= off) ? lsb[tid - off] : 0;
    __syncthreads();
    lsb[tid] += t;
    __syncthreads();
  }
  int cnt = bcnt[b];
  int rawbase = lsb[b] - cnt;
  int pbase = ((rawbase + 7) & ~7) + b * 2048;  // 8-aligned, disjoint per bucket
  const uint* B = bkt + (size_t)b * BCAP;
  for (int i = tid; i < cnt; i += 256) atomicAdd(&lhist[B[i] & 255], 1);
  __syncthreads();
  int v = lhist[tid];
  int pv = (v + 7) & ~7;
  lofs[tid] = pv;
  __syncthreads();
  for (int off = 1; off < 256; off <<= 1) {
    int t = (tid >= off) ? lofs[tid - off] : 0;
    __syncthreads();
    lofs[tid] += t;
    __syncthreads();
  }
  int excl = lofs[tid] - pv;
  int n = b * 256 + tid;
  if (n < NN) {
    offs[n] = pbase + excl;
    dinv[n] = rsqrtf((float)(v + 1));
    deg[n] = v;
    atomicAdd(&lh2[min(v, 63)], 1);
    for (int k = v; k < pv; k++) col[pbase + excl + k] = NN;  // sentinel pad
  }
  lcur[tid] = excl;
  __syncthreads();
  if (tid < 64 && lh2[tid]) atomicAdd(&ghist[tid], lh2[tid]);
  if (b == 0 && tid == 0) dinv[NN] = 0.f;
  for (int i = tid; i < cnt; i += 256) {
    uint e = B[i];
    int p = atomicAdd(&lcur[e & 255], 1);
    col[pbase + p] = (int)(e >> 8);
  }
}

// build DESCENDING degree-sorted permutation (heavy blocks scheduled first).

__global__ __launch_bounds__(256) void k_dperm(const int* __restrict__ deg,
                                               const int* __restrict__ ghist,
                                               int* __restrict__ gcur,
                                               int* __restrict__ perm) {
  __shared__ int lhist[64];
  __shared__ int lbase[64];
  int tid = threadIdx.x;
  if (tid < 64) lhist[tid] = 0;
  __syncthreads();
  int n = blockIdx.x * 256 + tid;
  int d = 0, rk = 0;
  if (n < NN) {
    d = min(deg[n], 63);
    rk = atomicAdd(&lhist[d], 1);
  }
  __syncthreads();
  if (tid < 64) {
    int s = 0;
    for (int i = tid + 1; i < 64; i++) s += ghist[i];
    if (lhist[tid]) lbase[tid] = s + atomicAdd(&gcur[tid], lhist[tid]);
  }
  __syncthreads();
  if (n < NN) perm[lbase[d] + rk] = n;
}

// ---------------- merged prep: u = f16(x*dinv) + Wt transpose + sentinel-row zero ----

__global__ __launch_bounds__(256) void k_prep(const float* __restrict__ x,
                                              const float* __restrict__ dinv,
                                              const float* __restrict__ W0,
                                              const float* __restrict__ Wg,
                                              ushort* __restrict__ u,
                                              ushort* __restrict__ Wt0,
                                              ushort* __restrict__ Wtg,
                                              ushort* __restrict__ g1,
                                              ushort* __restrict__ g2) {
  int idx = blockIdx.x * 256 + threadIdx.x;
  if (idx < UPN) {
    int n = idx >> 4;
    float4 v = ((const float4*)x)[idx];
    float d = dinv[n];
    union { ushort us[4]; uint2 q; } o;
    o.us[0] = f2h(v.x * d);
    o.us[1] = f2h(v.y * d);
    o.us[2] = f2h(v.z * d);
    o.us[3] = f2h(v.w * d);
    ((uint2*)u)[idx] = o.q;
  } else {
    int j = idx - UPN;
    if (j < DINv * GBv) {
      int c = j >> 6, k = j & 63;
      Wt0[j] = f2h(W0[k * GBv + c]);
    } else if (j < CONVN) {
      int e = j - DINv * GBv;
      int i = e >> 14, rem = e & 16383;
      int c = rem >> 7, k = rem & 127;
      Wtg[e] = f2h(Wg[i * GBv * GBv + k * GBv + c]);
    } else if (j < CONVN + ZEXT) {
      int z = j - CONVN;
      if (z < 64) u[(size_t)NN * DINv + z] = 0;
      else if (z < 192) g1[(size_t)NN * GBv + (z - 64)] = 0;
      else g2[(size_t)NN * GBv + (z - 192)] = 0;
    }
  }
}

// ---------------- FUSED layer: CSR aggregate -> LDS tile -> MFMA matmul ----------------
// 512 threads (8 waves) per 64-row tile. LDS trimmed to 54,016 B -> 3 blocks/CU
// (24 waves/CU latency hiding). Branchless sentinel-padded gather, aligned int4 col
// loads. MODE: 0 pure-sum; 1 relu*dinv; 2 relu(BN)*dinv (scale/shift per-thread).
// OUTF: epilogue writes relu(y+b)*dinv[node] so the NEXT layer can use MODE0.

template <int K, int MODE, bool STATS, bool OUTF>
__global__ __launch_bounds__(512, 6) void k_layer(const ushort* __restrict__ Gin,
                                                  const int* __restrict__ col,
                                                  const int* __restrict__ offs,
                                                  const int* __restrict__ deg,
                                                  const float* __restrict__ dinv,
                                                  const int* __restrict__ perm,
                                                  const float* __restrict__ st,
                                                  const float* __restrict__ gamma,
                                                  const float* __restrict__ beta,
                                                  const ushort* __restrict__ Wt,
                                                  const float* __restrict__ bias,
                                                  float* __restrict__ stG,
                                                  ushort* __restrict__ Gout) {
  constexpr int VEC = K / 16;
  constexpr int KP = K + 8;
  constexpr int CP = 136;
  constexpr bool REUSE = (K == 128);
  __shared__ __attribute__((aligned(16))) _Float16 sW[128 * KP];
  __shared__ __attribute__((aligned(16))) _Float16 sA[64 * KP];
  __shared__ float sB[128];
  __shared__ float ssum[128], ssq[128];
  __shared__ float sDn[64];
  // C staging: K=128 reuses sA (dead after MFMA); K=64 reuses sW (128*72 >= 64*136)
  _Float16* sC = REUSE ? sA : sW;
  int tid = threadIdx.x;

  {
    constexpr int CH = K / 8;
    for (int i = tid; i < 128 * CH; i += 512) {
      int c = i / CH, ch = i - c * CH;
      *(uint4*)&sW[c * KP + ch * 8] = ((const uint4*)Wt)[i];
    }
  }
  if (tid < 128) {
    sB[tid] = bias[tid];
    if constexpr (STATS) {
      ssum[tid] = 0.f;
      ssq[tid] = 0.f;
    }
  }

  int w = tid >> 6, lane = tid & 63;
  int quad = lane >> 4, m = lane & 15;
  int row0 = blockIdx.x * 64;

  float sc[VEC], tc[VEC];
  if constexpr (MODE == 2) {
#pragma unroll
    for (int v = 0; v < VEC; v++) {
      int c = m * VEC + v;
      float mu = st[c] * (1.f / NN);
      float var = st[128 + c] * (1.f / NN) - mu * mu;
      float s = rsqrtf(var + 1e-5f) * gamma[c];
      sc[v] = s;
      tc[v] = beta[c] - mu * s;
    }
  }

  union U { uint4 v4; uint2 v2; ushort us[8]; };
  auto loadrow = [&](int s) {
    U u;
    const ushort* p = Gin + (long)s * K + m * VEC;
    if constexpr (VEC == 8) u.v4 = *(const uint4*)p;
    else u.v2 = *(const uint2*)p;
    return u;
  };

  // ---- phase A: aggregate 64 nodes into sA over 2 rounds ----
  for (int rnd = 0; rnd < 2; rnd++) {
    int r = rnd * 32 + w * 4 + quad;
    int idx = row0 + r;
    float acc[VEC];
#pragma unroll
    for (int v = 0; v < VEC; v++) acc[v] = 0.f;
    float dn = 0.f;
    if (idx < NN) {
      int n = perm[idx];
      dn = dinv[n];
      auto addrow = [&](U u, float wv) {
#pragma unroll
        for (int v = 0; v < VEC; v++) {
          float g = h2f(u.us[v]);
          if constexpr (MODE == 2) g = fmaxf(g * sc[v] + tc[v], 0.f);
          else if constexpr (MODE == 1) g = fmaxf(g, 0.f);
          acc[v] += g * wv;
        }
      };
      addrow(loadrow(n), (MODE == 0) ? 1.f : dn);
      int s0 = offs[n];
      int pcnt = (deg[n] + 7) & ~7;
      const int* cp = col + s0;
      for (int j = 0; j < pcnt; j += 8) {
        int4 ca = *(const int4*)(cp + j);
        int4 cb = *(const int4*)(cp + j + 4);
        int si[8] = {ca.x, ca.y, ca.z, ca.w, cb.x, cb.y, cb.z, cb.w};
        U uu[8];
#pragma unroll
        for (int t = 0; t < 8; t++) uu[t] = loadrow(si[t]);
        float wt[8];
#pragma unroll
        for (int t = 0; t < 8; t++) wt[t] = (MODE == 0) ? 1.f : dinv[si[t]];
#pragma unroll
        for (int t = 0; t < 8; t++) addrow(uu[t], wt[t]);
      }
    }
    if constexpr (OUTF) {
      if (m == 0) sDn[r] = dn;
    }
    U o;
#pragma unroll
    for (int v = 0; v < VEC; v++) o.us[v] = f2h(acc[v] * dn);
    _Float16* ap = &sA[r * KP + m * VEC];
    if constexpr (VEC == 8) *(uint4*)ap = o.v4;
    else *(uint2*)ap = o.v2;
  }
  __syncthreads();

  // ---- phase B: MFMA tile, 8 waves = 4 row-groups x 2 col-halves ----
  int wr = w >> 1, wc = w & 1;
  f32x4 acc2[4];
#pragma unroll
  for (int ct = 0; ct < 4; ct++) acc2[ct] = (f32x4){0.f, 0.f, 0.f, 0.f};
  const _Float16* pa = &sA[(16 * wr + m) * KP + quad * 8];
#pragma unroll
  for (int ks = 0; ks < K; ks += 32) {
    f16x8 a = *(const f16x8*)(pa + ks);
#pragma unroll
    for (int ct = 0; ct < 4; ct++) {
      int c = wc * 64 + ct * 16 + m;
      f16x8 bfr = *(const f16x8*)&sW[c * KP + ks + quad * 8];
      acc2[ct] = __builtin_amdgcn_mfma_f32_16x16x32_f16(a, bfr, acc2[ct], 0, 0, 0);
    }
  }

  int crow = 16 * wr + quad * 4;
  float ps[4], pq[4];
  if constexpr (STATS) {
#pragma unroll
    for (int ct = 0; ct < 4; ct++) {
      int c = wc * 64 + ct * 16 + m;
      float bb = sB[c];
      ps[ct] = 0.f;
      pq[ct] = 0.f;
#pragma unroll
      for (int r = 0; r < 4; r++) {
        if (row0 + crow + r < NN) {
          float g = acc2[ct][r] + bb;
          ps[ct] += g;
          pq[ct] += g * g;
        }
      }
    }
  }
  __syncthreads();  // sA/sW about to be reused as sC

  float dvr[4];
  if constexpr (OUTF) {
#pragma unroll
    for (int r = 0; r < 4; r++) dvr[r] = sDn[crow + r];
  }
#pragma unroll
  for (int ct = 0; ct < 4; ct++) {
    int c = wc * 64 + ct * 16 + m;
    float bb = sB[c];
#pragma unroll
    for (int r = 0; r < 4; r++) {
      float y = acc2[ct][r] + bb;
      if constexpr (OUTF) y = fmaxf(y, 0.f) * dvr[r];
      sC[(crow + r) * CP + c] = (_Float16)y;
    }
  }
  __syncthreads();

  {
    int r = tid >> 3;
    int c0 = (tid & 7) * 16;
    int idx2 = row0 + r;
    if (idx2 < NN) {
      int node = perm[idx2];
      const uint4* srcp = (const uint4*)&sC[r * CP + c0];
      uint4* dst = (uint4*)(Gout + (long)node * 128 + c0);
      dst[0] = srcp[0];
      dst[1] = srcp[1];
    }
  }

  if constexpr (STATS) {
#pragma unroll
    for (int ct = 0; ct < 4; ct++) {
      float s = ps[ct], q = pq[ct];
      s += __shfl_xor(s, 16);
      q += __shfl_xor(q, 16);
      s += __shfl_xor(s, 32);
      q += __shfl_xor(q, 32);
      if (quad == 0) {
        atomicAdd(&ssum[wc * 64 + ct * 16 + m], s);
        atomicAdd(&ssq[wc * 64 + ct * 16 + m], q);
      }
    }
    __syncthreads();
    if (tid < 128) {
      int c = (tid + blockIdx.x * 8) & 127;
      atomicAdd(&stG[c], ssum[c]);
      atomicAdd(&stG[128 + c], ssq[c]);
    }
  }
}

// ---------------- pool: per-graph segmented reduction (batch sorted) ----------------

__global__ __launch_bounds__(128) void k_pool2(const ushort* __restrict__ G,
                                               const float* __restrict__ st,
                                               const float* __restrict__ gamma,
                                               const float* __restrict__ beta,
                                               const int* __restrict__ batch,
                                               float* __restrict__ hp) {
  __shared__ int sse[2];
  int g = blockIdx.x;
  int c = threadIdx.x;
  if (c < 2) {
    int key = g + c;
    int lo = 0, hi = NN;
    while (lo < hi) {
      int mid = (lo + hi) >> 1;
      if (batch[mid] < key) lo = mid + 1;
      else hi = mid;
    }
    sse[c] = lo;
  }
  __syncthreads();
  int s = sse[0], e = sse[1];
  float m = st[c] * (1.f / NN);
  float v = st[128 + c] * (1.f / NN) - m * m;
  float sc = rsqrtf(v + 1e-5f) * gamma[c];
  float tc = beta[c] - m * sc;
  float a0 = 0.f, a1 = 0.f, a2 = 0.f, a3 = 0.f;
  int n = s;
  for (; n + 3 < e; n += 4) {
    float g0 = h2f(G[(long)(n + 0) * 128 + c]);
    float g1 = h2f(G[(long)(n + 1) * 128 + c]);
    float g2 = h2f(G[(long)(n + 2) * 128 + c]);
    float g3 = h2f(G[(long)(n + 3) * 128 + c]);
    a0 += fmaxf(g0 * sc + tc, 0.f);
    a1 += fmaxf(g1 * sc + tc, 0.f);
    a2 += fmaxf(g2 * sc + tc, 0.f);
    a3 += fmaxf(g3 * sc + tc, 0.f);
  }
  for (; n < e; n++) a0 += fmaxf(h2f(G[(long)n * 128 + c]) * sc + tc, 0.f);
  hp[(long)g * 128 + c] = (a0 + a1) + (a2 + a3);
}

// ---------------- head column stats (fp32) ----------------

__global__ void k_colstats(const float* __restrict__ X, int rows, float* __restrict__ st) {
  int c = threadIdx.x;
  int C = blockDim.x;
  float s = 0.f, q = 0.f;
  for (int r = blockIdx.x; r < rows; r += gridDim.x) {
    float v = X[(long)r * C + c];
    s += v;
    q += v * v;
  }
  atomicAdd(&st[c], s);
  atomicAdd(&st[C + c], q);
}

// ---------------- MLP head ----------------

template <int KIN, int MODE>
__global__ __launch_bounds__(256) void k_fc(const float* __restrict__ X,
                                            const float* __restrict__ W,
                                            const float* __restrict__ b,
                                            const float* __restrict__ st,
                                            const float* __restrict__ gamma,
                                            const float* __restrict__ beta,
                                            float* __restrict__ Y) {
  __shared__ float sx[KIN];
  int g = blockIdx.x;
  int c = threadIdx.x;
  for (int k = c; k < KIN; k += 256) {
    float v = X[(long)g * KIN + k];
    if constexpr (MODE == 2) {
      float m = st[k] * (1.f / GGv);
      float var = st[KIN + k] * (1.f / GGv) - m * m;
      v = fmaxf((v - m) * rsqrtf(var + 1e-5f) * gamma[k] + beta[k], 0.f);
    }
    sx[k] = v;
  }
  __syncthreads();
  float acc = b[c];
#pragma unroll 8
  for (int k = 0; k < KIN; k++) acc += sx[k] * W[(long)k * 256 + c];
  Y[(long)g * 256 + c] = (MODE == 0) ? fmaxf(acc, 0.f) : acc;
}

__global__ __launch_bounds__(256) void k_out(const float* __restrict__ X,
                                             const float* __restrict__ st,
                                             const float* __restrict__ gamma,
                                             const float* __restrict__ beta,
                                             const float* __restrict__ Wout,
                                             const float* __restrict__ bout,
                                             float* __restrict__ out) {
  int g = blockIdx.x * 4 + (threadIdx.x >> 6);
  int l = threadIdx.x & 63;
  float a0 = 0.f, a1 = 0.f;
  for (int k = l; k < LBv; k += 64) {
    float z = X[(long)g * LBv + k];
    float m = st[k] * (1.f / GGv);
    float var = st[LBv + k] * (1.f / GGv) - m * m;
    float x = fmaxf((z - m) * rsqrtf(var + 1e-5f) * gamma[k] + beta[k], 0.f);
    a0 += x * Wout[2 * k];
    a1 += x * Wout[2 * k + 1];
  }
  for (int off = 32; off > 0; off >>= 1) {
    a0 += __shfl_down(a0, off);
    a1 += __shfl_down(a1, off);
  }
  if (l == 0) {
    out[2 * g] = a0 + bout[0];
    out[2 * g + 1] = a1 + bout[1];
  }
}

// ---------------- launch ----------------

extern "C" void kernel_launch(void* const* d_in, const int* in_sizes, int n_in,
                              void* d_out, int out_size, void* d_ws, size_t ws_size,
                              hipStream_t stream) {
  const float* x = (const float*)d_in[0];
  const int* ei = (const int*)d_in[1];
  const int* batch = (const int*)d_in[2];
  const float* W0 = (const float*)d_in[4];
  const float* b0 = (const float*)d_in[5];
  const float* Wg = (const float*)d_in[6];
  const float* bg = (const float*)d_in[7];
  const float* gamma_g = (const float*)d_in[8];
  const float* beta_g = (const float*)d_in[9];
  const float* Wl0 = (const float*)d_in[10];
  const float* bl0 = (const float*)d_in[11];
  const float* Wl = (const float*)d_in[12];
  const float* bl = (const float*)d_in[13];
  const float* gamma_l = (const float*)d_in[14];
  const float* beta_l = (const float*)d_in[15];
  const float* Wout = (const float*)d_in[16];
  const float* bout = (const float*)d_in[17];
  float* out = (float*)d_out;

  char* w = (char*)d_ws;
  auto alloc = [&](size_t bytes) {
    void* p = (void*)w;
    w += (bytes + 255) & ~(size_t)255;
    return p;
  };
  // zero-initialized span: bcnt | stAll | ghist | gcur
  int* bcnt = (int*)alloc((size_t)NB * 4);
  float* stAll = (float*)alloc((size_t)(4 * 256 + 2 * 512) * 4);
  int* ghist = (int*)alloc((size_t)64 * 4);
  int* gcur = (int*)alloc((size_t)64 * 4);
  size_t zspan = (char*)w - (char*)bcnt;
  // rest
  uint* bkt = (uint*)alloc((size_t)NB * BCAP * 4);
  int* offs = (int*)alloc((size_t)(NN + 1) * 4);
  int* col = (int*)alloc((size_t)(EE + NB * 2048 + 8192) * 4);
  float* dinv = (float*)alloc((size_t)(NN + 1) * 4);
  int* deg = (int*)alloc((size_t)NN * 4);
  int* perm = (int*)alloc((size_t)NN * 4);
  ushort* u = (ushort*)alloc((size_t)(NN + 1) * DINv * 2);
  ushort* g1 = (ushort*)alloc((size_t)(NN + 1) * GBv * 2);
  ushort* g2 = (ushort*)alloc((size_t)(NN + 1) * GBv * 2);
  ushort* Wt0 = (ushort*)alloc((size_t)DINv * GBv * 2);
  ushort* Wtg = (ushort*)alloc((size_t)GDv * GBv * GBv * 2);
  float* hp = (float*)alloc((size_t)GGv * GBv * 4);
  float* m1 = (float*)alloc((size_t)GGv * LBv * 4);
  float* m2 = (float*)alloc((size_t)GGv * LBv * 4);

  float* stg = stAll;
  float* sth0 = stAll + 4 * 256;
  float* sth1 = sth0 + 512;

  hipMemsetAsync(bcnt, 0, zspan, stream);

  k_bucket<<<NBT, 256, 0, stream>>>(ei, bcnt, bkt);
  k_csr<<<NB, 256, 0, stream>>>(bkt, bcnt, offs, dinv, col, deg, ghist);
  k_dperm<<<NB, 256, 0, stream>>>(deg, ghist, gcur, perm);
  k_prep<<<(UPN + CONVN + ZEXT + 255) / 256, 256, 0, stream>>>(x, dinv, W0, Wg, u, Wt0,
                                                               Wtg, g1, g2);

  // layer 0: agg(u) @ W0 + b0; epilogue writes relu(y)*dinv -> g1 (so layer 1 is MODE0)
  k_layer<64, 0, false, true><<<NTILES, 512, 0, stream>>>(
      u, col, offs, deg, dinv, perm, nullptr, nullptr, nullptr, Wt0, b0, nullptr, g1);
  // layer 1: pure-sum gather of g1 -> agg @ Wg0 + bg0 -> g2 (raw), stats -> stg[0]
  k_layer<128, 0, true, false><<<NTILES, 512, 0, stream>>>(
      g1, col, offs, deg, dinv, perm, nullptr, nullptr, nullptr, Wtg, bg, stg, g2);
  // layers 2..4: BN+relu fold on input, ping-pong g2/g1
  for (int i = 1; i < GDv; i++) {
    const ushort* gin = (i & 1) ? g2 : g1;
    ushort* gout = (i & 1) ? g1 : g2;
    k_layer<128, 2, true, false><<<NTILES, 512, 0, stream>>>(
        gin, col, offs, deg, dinv, perm, stg + (size_t)(i - 1) * 256,
        gamma_g + (size_t)(i - 1) * GBv, beta_g + (size_t)(i - 1) * GBv,
        Wtg + (size_t)i * GBv * GBv, bg + (size_t)i * GBv, stg + (size_t)i * 256, gout);
  }
  // final layer output is g1 (i=3 writes g1)

  // pool with final BN+relu fused
  k_pool2<<<GGv, 128, 0, stream>>>(g1, stg + 3 * 256, gamma_g + 3 * GBv, beta_g + 3 * GBv,
                                   batch, hp);

  // head
  k_fc<GBv, 0><<<GGv, 256, 0, stream>>>(hp, Wl0, bl0, nullptr, nullptr, nullptr, m1);
  k_fc<LBv, 1><<<GGv, 256, 0, stream>>>(m1, Wl, bl, nullptr, nullptr, nullptr, m2);
  k_colstats<<<256, LBv, 0, stream>>>(m2, GGv, sth0);
  k_fc<LBv, 2><<<GGv, 256, 0, stream>>>(m2, Wl + (size_t)LBv * LBv, bl + LBv, sth0,
                                        gamma_l, beta_l, m1);
  k_colstats<<<256, LBv, 0, stream>>>(m1, GGv, sth1);
  k_out<<<GGv / 4, 256, 0, stream>>>(m1, sth1, gamma_l + LBv, beta_l + LBv, Wout, bout, out);
}

// Round 4
// 407.772 us; speedup vs baseline: 1.2113x; 1.2113x over previous
//
#include <hip/hip_runtime.h>

#define NN 50000
#define EE 640000
#define DINv 64
#define GBv 128
#define GDv 4
#define LBv 256
#define LDv 2
#define GGv 1024

#define NB 196       // coarse buckets (256 nodes each)
#define BCAP 4096    // bucket capacity
#define BTILE 4096   // edges per k_bucket block
#define NBT ((EE + BTILE - 1) / BTILE)  // 157

#define NTILES ((NN + 63) / 64)  // 782 row-tiles
#define UPN (NN * 16)            // uprep float4 groups
#define CONVN (DINv * GBv + GDv * GBv * GBv)
#define ZEXT 320                 // sentinel-row zero elements (64 + 128 + 128)

typedef _Float16 f16x8 __attribute__((ext_vector_type(8)));
typedef float f32x4 __attribute__((ext_vector_type(4)));

__device__ __forceinline__ float h2f(ushort u) {
  union { ushort u; _Float16 h; } x;
  x.u = u;
  return (float)x.h;
}
__device__ __forceinline__ ushort f2h(float f) {
  union { ushort u; _Float16 h; } x;
  x.h = (_Float16)f;
  return x.u;
}

// ---------------- stage 1: coarse bucket sort (dst>>8) ----------------

__global__ __launch_bounds__(256) void k_bucket(const int* __restrict__ ei,
                                                int* __restrict__ bcnt,
                                                uint* __restrict__ bkt) {
  __shared__ int lcnt[NB];
  __shared__ int lbase[NB];
  __shared__ int gbase[NB];
  __shared__ int ls[256];
  __shared__ uint stage[BTILE];
  __shared__ ushort sb[BTILE];
  int tid = threadIdx.x;
  int t0 = blockIdx.x * BTILE;
  int cnt = min(BTILE, EE - t0);
  for (int i = tid; i < NB; i += 256) lcnt[i] = 0;
  __syncthreads();

  uint en[16];
  int bb[16], rk[16];
  int nper = (cnt + 255) >> 8;
  for (int k = 0; k < nper; k++) {
    int e = k * 256 + tid;
    if (e < cnt) {
      int src = ei[t0 + e];
      int dst = ei[EE + t0 + e];
      int b = dst >> 8;
      en[k] = ((uint)src << 8) | (uint)(dst & 255);
      bb[k] = b;
      rk[k] = atomicAdd(&lcnt[b], 1);
    } else {
      bb[k] = -1;
    }
  }
  __syncthreads();

  int v = (tid < NB) ? lcnt[tid] : 0;
  ls[tid] = v;
  __syncthreads();
  for (int off = 1; off < 256; off <<= 1) {
    int t = (tid >= off) ? ls[tid - off] : 0;
    __syncthreads();
    ls[tid] += t;
    __syncthreads();
  }
  if (tid < NB) {
    lbase[tid] = ls[tid] - v;
    gbase[tid] = atomicAdd(&bcnt[tid], v);
  }
  __syncthreads();

  for (int k = 0; k < nper; k++) {
    if (bb[k] >= 0) {
      int slot = lbase[bb[k]] + rk[k];
      stage[slot] = en[k];
      sb[slot] = (ushort)bb[k];
    }
  }
  __syncthreads();

  for (int i = tid; i < cnt; i += 256) {
    int b = sb[i];
    bkt[(size_t)b * BCAP + gbase[b] + (i - lbase[b])] = stage[i];
  }
}

// ---------------- stage 2: per-bucket fine CSR (8-padded with sentinel NN) ----------
// Each node's col segment is padded to a multiple of 8 with sentinel index NN (a zero
// row with dinv[NN]=0) -> branchless 8-wide gather with aligned int4 col loads, zero
// wasted bandwidth (sentinel row is cache-hot). deg[] stores the raw (uncapped) degree.

__global__ __launch_bounds__(256) void k_csr(const uint* __restrict__ bkt,
                                             const int* __restrict__ bcnt,
                                             int* __restrict__ offs,
                                             float* __restrict__ dinv,
                                             int* __restrict__ col,
                                             int* __restrict__ deg,
                                             int* __restrict__ ghist) {
  __shared__ int lhist[256];
  __shared__ int lofs[256];
  __shared__ int lcur[256];
  __shared__ int lsb[256];
  __shared__ int lh2[64];
  int b = blockIdx.x;
  int tid = threadIdx.x;
  int bv = (tid < NB) ? bcnt[tid] : 0;
  lsb[tid] = bv;
  lhist[tid] = 0;
  if (tid < 64) lh2[tid] = 0;
  __syncthreads();
  for (int off = 1; off < 256; off <<= 1) {
    int t = (tid >= off) ? lsb[tid - off] : 0;
    __syncthreads();
    lsb[tid] += t;
    __syncthreads();
  }
  int cnt = bcnt[b];
  int rawbase = lsb[b] - cnt;
  int pbase = ((rawbase + 7) & ~7) + b * 2048;  // 8-aligned, disjoint per bucket
  const uint* B = bkt + (size_t)b * BCAP;
  for (int i = tid; i < cnt; i += 256) atomicAdd(&lhist[B[i] & 255], 1);
  __syncthreads();
  int v = lhist[tid];
  int pv = (v + 7) & ~7;
  lofs[tid] = pv;
  __syncthreads();
  for (int off = 1; off < 256; off <<= 1) {
    int t = (tid >= off) ? lofs[tid - off] : 0;
    __syncthreads();
    lofs[tid] += t;
    __syncthreads();
  }
  int excl = lofs[tid] - pv;
  int n = b * 256 + tid;
  if (n < NN) {
    offs[n] = pbase + excl;
    dinv[n] = rsqrtf((float)(v + 1));
    deg[n] = v;
    atomicAdd(&lh2[min(v, 63)], 1);
    for (int k = v; k < pv; k++) col[pbase + excl + k] = NN;  // sentinel pad
  }
  lcur[tid] = excl;
  __syncthreads();
  if (tid < 64 && lh2[tid]) atomicAdd(&ghist[tid], lh2[tid]);
  if (b == 0 && tid == 0) dinv[NN] = 0.f;
  for (int i = tid; i < cnt; i += 256) {
    uint e = B[i];
    int p = atomicAdd(&lcur[e & 255], 1);
    col[pbase + p] = (int)(e >> 8);
  }
}

// build DESCENDING degree-sorted permutation (heavy blocks scheduled first).

__global__ __launch_bounds__(256) void k_dperm(const int* __restrict__ deg,
                                               const int* __restrict__ ghist,
                                               int* __restrict__ gcur,
                                               int* __restrict__ perm) {
  __shared__ int lhist[64];
  __shared__ int lbase[64];
  int tid = threadIdx.x;
  if (tid < 64) lhist[tid] = 0;
  __syncthreads();
  int n = blockIdx.x * 256 + tid;
  int d = 0, rk = 0;
  if (n < NN) {
    d = min(deg[n], 63);
    rk = atomicAdd(&lhist[d], 1);
  }
  __syncthreads();
  if (tid < 64) {
    int s = 0;
    for (int i = tid + 1; i < 64; i++) s += ghist[i];
    if (lhist[tid]) lbase[tid] = s + atomicAdd(&gcur[tid], lhist[tid]);
  }
  __syncthreads();
  if (n < NN) perm[lbase[d] + rk] = n;
}

// ---------------- merged prep: u = f16(x*dinv) + Wt transpose + sentinel-row zero ----

__global__ __launch_bounds__(256) void k_prep(const float* __restrict__ x,
                                              const float* __restrict__ dinv,
                                              const float* __restrict__ W0,
                                              const float* __restrict__ Wg,
                                              ushort* __restrict__ u,
                                              ushort* __restrict__ Wt0,
                                              ushort* __restrict__ Wtg,
                                              ushort* __restrict__ g1,
                                              ushort* __restrict__ g2) {
  int idx = blockIdx.x * 256 + threadIdx.x;
  if (idx < UPN) {
    int n = idx >> 4;
    float4 v = ((const float4*)x)[idx];
    float d = dinv[n];
    union { ushort us[4]; uint2 q; } o;
    o.us[0] = f2h(v.x * d);
    o.us[1] = f2h(v.y * d);
    o.us[2] = f2h(v.z * d);
    o.us[3] = f2h(v.w * d);
    ((uint2*)u)[idx] = o.q;
  } else {
    int j = idx - UPN;
    if (j < DINv * GBv) {
      int c = j >> 6, k = j & 63;
      Wt0[j] = f2h(W0[k * GBv + c]);
    } else if (j < CONVN) {
      int e = j - DINv * GBv;
      int i = e >> 14, rem = e & 16383;
      int c = rem >> 7, k = rem & 127;
      Wtg[e] = f2h(Wg[i * GBv * GBv + k * GBv + c]);
    } else if (j < CONVN + ZEXT) {
      int z = j - CONVN;
      if (z < 64) u[(size_t)NN * DINv + z] = 0;
      else if (z < 192) g1[(size_t)NN * GBv + (z - 64)] = 0;
      else g2[(size_t)NN * GBv + (z - 192)] = 0;
    }
  }
}

// ---------------- FUSED layer: CSR aggregate -> LDS tile -> MFMA matmul ----------------
// 512 threads (8 waves) per 64-row tile. launch_bounds(512,2): VGPR cap 256 so the
// 8-wide gather (uu[8]+acc[8]+addrs ~ 100 VGPR) NEVER spills to scratch (round-3
// lesson: forced 40 VGPR cost +90MB of scratch HBM traffic). LDS 53,760B allows
// 3 blocks/CU if the allocator lands <=85 VGPR, else 2. Branchless sentinel gather.
// MODE: 0 pure-sum; 1 relu*dinv; 2 relu(BN)*dinv. OUTF: write relu(y+b)*dinv[node].

template <int K, int MODE, bool STATS, bool OUTF>
__global__ __launch_bounds__(512, 2) void k_layer(const ushort* __restrict__ Gin,
                                                  const int* __restrict__ col,
                                                  const int* __restrict__ offs,
                                                  const int* __restrict__ deg,
                                                  const float* __restrict__ dinv,
                                                  const int* __restrict__ perm,
                                                  const float* __restrict__ st,
                                                  const float* __restrict__ gamma,
                                                  const float* __restrict__ beta,
                                                  const ushort* __restrict__ Wt,
                                                  const float* __restrict__ bias,
                                                  float* __restrict__ stG,
                                                  ushort* __restrict__ Gout) {
  constexpr int VEC = K / 16;
  constexpr int KP = K + 8;
  constexpr int CP = 136;
  constexpr bool REUSE = (K == 128);
  __shared__ __attribute__((aligned(16))) _Float16 sW[128 * KP];
  __shared__ __attribute__((aligned(16))) _Float16 sA[64 * KP];
  __shared__ float sB[128];
  __shared__ float ssum[128], ssq[128];
  __shared__ float sDn[64];
  // C staging: K=128 reuses sA (dead after MFMA); K=64 reuses sW (128*72 >= 64*136)
  _Float16* sC = REUSE ? sA : sW;
  int tid = threadIdx.x;

  {
    constexpr int CH = K / 8;
    for (int i = tid; i < 128 * CH; i += 512) {
      int c = i / CH, ch = i - c * CH;
      *(uint4*)&sW[c * KP + ch * 8] = ((const uint4*)Wt)[i];
    }
  }
  if (tid < 128) {
    sB[tid] = bias[tid];
    if constexpr (STATS) {
      ssum[tid] = 0.f;
      ssq[tid] = 0.f;
    }
  }

  int w = tid >> 6, lane = tid & 63;
  int quad = lane >> 4, m = lane & 15;
  int row0 = blockIdx.x * 64;

  float sc[VEC], tc[VEC];
  if constexpr (MODE == 2) {
#pragma unroll
    for (int v = 0; v < VEC; v++) {
      int c = m * VEC + v;
      float mu = st[c] * (1.f / NN);
      float var = st[128 + c] * (1.f / NN) - mu * mu;
      float s = rsqrtf(var + 1e-5f) * gamma[c];
      sc[v] = s;
      tc[v] = beta[c] - mu * s;
    }
  }

  union U { uint4 v4; uint2 v2; ushort us[8]; };
  auto loadrow = [&](int s) {
    U u;
    const ushort* p = Gin + (long)s * K + m * VEC;
    if constexpr (VEC == 8) u.v4 = *(const uint4*)p;
    else u.v2 = *(const uint2*)p;
    return u;
  };

  // ---- phase A: aggregate 64 nodes into sA over 2 rounds ----
  for (int rnd = 0; rnd < 2; rnd++) {
    int r = rnd * 32 + w * 4 + quad;
    int idx = row0 + r;
    float acc[VEC];
#pragma unroll
    for (int v = 0; v < VEC; v++) acc[v] = 0.f;
    float dn = 0.f;
    if (idx < NN) {
      int n = perm[idx];
      dn = dinv[n];
      auto addrow = [&](U u, float wv) {
#pragma unroll
        for (int v = 0; v < VEC; v++) {
          float g = h2f(u.us[v]);
          if constexpr (MODE == 2) g = fmaxf(g * sc[v] + tc[v], 0.f);
          else if constexpr (MODE == 1) g = fmaxf(g, 0.f);
          acc[v] += g * wv;
        }
      };
      addrow(loadrow(n), (MODE == 0) ? 1.f : dn);
      int s0 = offs[n];
      int pcnt = (deg[n] + 7) & ~7;
      const int* cp = col + s0;
      for (int j = 0; j < pcnt; j += 8) {
        int4 ca = *(const int4*)(cp + j);
        int4 cb = *(const int4*)(cp + j + 4);
        int si[8] = {ca.x, ca.y, ca.z, ca.w, cb.x, cb.y, cb.z, cb.w};
        U uu[8];
#pragma unroll
        for (int t = 0; t < 8; t++) uu[t] = loadrow(si[t]);
        float wt[8];
#pragma unroll
        for (int t = 0; t < 8; t++) wt[t] = (MODE == 0) ? 1.f : dinv[si[t]];
#pragma unroll
        for (int t = 0; t < 8; t++) addrow(uu[t], wt[t]);
      }
    }
    if constexpr (OUTF) {
      if (m == 0) sDn[r] = dn;
    }
    U o;
#pragma unroll
    for (int v = 0; v < VEC; v++) o.us[v] = f2h(acc[v] * dn);
    _Float16* ap = &sA[r * KP + m * VEC];
    if constexpr (VEC == 8) *(uint4*)ap = o.v4;
    else *(uint2*)ap = o.v2;
  }
  __syncthreads();

  // ---- phase B: MFMA tile, 8 waves = 4 row-groups x 2 col-halves ----
  int wr = w >> 1, wc = w & 1;
  f32x4 acc2[4];
#pragma unroll
  for (int ct = 0; ct < 4; ct++) acc2[ct] = (f32x4){0.f, 0.f, 0.f, 0.f};
  const _Float16* pa = &sA[(16 * wr + m) * KP + quad * 8];
#pragma unroll
  for (int ks = 0; ks < K; ks += 32) {
    f16x8 a = *(const f16x8*)(pa + ks);
#pragma unroll
    for (int ct = 0; ct < 4; ct++) {
      int c = wc * 64 + ct * 16 + m;
      f16x8 bfr = *(const f16x8*)&sW[c * KP + ks + quad * 8];
      acc2[ct] = __builtin_amdgcn_mfma_f32_16x16x32_f16(a, bfr, acc2[ct], 0, 0, 0);
    }
  }

  int crow = 16 * wr + quad * 4;
  float ps[4], pq[4];
  if constexpr (STATS) {
#pragma unroll
    for (int ct = 0; ct < 4; ct++) {
      int c = wc * 64 + ct * 16 + m;
      float bb = sB[c];
      ps[ct] = 0.f;
      pq[ct] = 0.f;
#pragma unroll
      for (int r = 0; r < 4; r++) {
        if (row0 + crow + r < NN) {
          float g = acc2[ct][r] + bb;
          ps[ct] += g;
          pq[ct] += g * g;
        }
      }
    }
  }
  __syncthreads();  // sA/sW about to be reused as sC

  float dvr[4];
  if constexpr (OUTF) {
#pragma unroll
    for (int r = 0; r < 4; r++) dvr[r] = sDn[crow + r];
  }
#pragma unroll
  for (int ct = 0; ct < 4; ct++) {
    int c = wc * 64 + ct * 16 + m;
    float bb = sB[c];
#pragma unroll
    for (int r = 0; r < 4; r++) {
      float y = acc2[ct][r] + bb;
      if constexpr (OUTF) y = fmaxf(y, 0.f) * dvr[r];
      sC[(crow + r) * CP + c] = (_Float16)y;
    }
  }
  __syncthreads();

  {
    int r = tid >> 3;
    int c0 = (tid & 7) * 16;
    int idx2 = row0 + r;
    if (idx2 < NN) {
      int node = perm[idx2];
      const uint4* srcp = (const uint4*)&sC[r * CP + c0];
      uint4* dst = (uint4*)(Gout + (long)node * 128 + c0);
      dst[0] = srcp[0];
      dst[1] = srcp[1];
    }
  }

  if constexpr (STATS) {
#pragma unroll
    for (int ct = 0; ct < 4; ct++) {
      float s = ps[ct], q = pq[ct];
      s += __shfl_xor(s, 16);
      q += __shfl_xor(q, 16);
      s += __shfl_xor(s, 32);
      q += __shfl_xor(q, 32);
      if (quad == 0) {
        atomicAdd(&ssum[wc * 64 + ct * 16 + m], s);
        atomicAdd(&ssq[wc * 64 + ct * 16 + m], q);
      }
    }
    __syncthreads();
    if (tid < 128) {
      int c = (tid + blockIdx.x * 8) & 127;
      atomicAdd(&stG[c], ssum[c]);
      atomicAdd(&stG[128 + c], ssq[c]);
    }
  }
}

// ---------------- pool: per-graph segmented reduction (batch sorted) ----------------

__global__ __launch_bounds__(128) void k_pool2(const ushort* __restrict__ G,
                                               const float* __restrict__ st,
                                               const float* __restrict__ gamma,
                                               const float* __restrict__ beta,
                                               const int* __restrict__ batch,
                                               float* __restrict__ hp) {
  __shared__ int sse[2];
  int g = blockIdx.x;
  int c = threadIdx.x;
  if (c < 2) {
    int key = g + c;
    int lo = 0, hi = NN;
    while (lo < hi) {
      int mid = (lo + hi) >> 1;
      if (batch[mid] < key) lo = mid + 1;
      else hi = mid;
    }
    sse[c] = lo;
  }
  __syncthreads();
  int s = sse[0], e = sse[1];
  float m = st[c] * (1.f / NN);
  float v = st[128 + c] * (1.f / NN) - m * m;
  float sc = rsqrtf(v + 1e-5f) * gamma[c];
  float tc = beta[c] - m * sc;
  float a0 = 0.f, a1 = 0.f, a2 = 0.f, a3 = 0.f;
  int n = s;
  for (; n + 3 < e; n += 4) {
    float g0 = h2f(G[(long)(n + 0) * 128 + c]);
    float g1 = h2f(G[(long)(n + 1) * 128 + c]);
    float g2 = h2f(G[(long)(n + 2) * 128 + c]);
    float g3 = h2f(G[(long)(n + 3) * 128 + c]);
    a0 += fmaxf(g0 * sc + tc, 0.f);
    a1 += fmaxf(g1 * sc + tc, 0.f);
    a2 += fmaxf(g2 * sc + tc, 0.f);
    a3 += fmaxf(g3 * sc + tc, 0.f);
  }
  for (; n < e; n++) a0 += fmaxf(h2f(G[(long)n * 128 + c]) * sc + tc, 0.f);
  hp[(long)g * 128 + c] = (a0 + a1) + (a2 + a3);
}

// ---------------- head column stats (fp32) ----------------

__global__ void k_colstats(const float* __restrict__ X, int rows, float* __restrict__ st) {
  int c = threadIdx.x;
  int C = blockDim.x;
  float s = 0.f, q = 0.f;
  for (int r = blockIdx.x; r < rows; r += gridDim.x) {
    float v = X[(long)r * C + c];
    s += v;
    q += v * v;
  }
  atomicAdd(&st[c], s);
  atomicAdd(&st[C + c], q);
}

// ---------------- MLP head ----------------

template <int KIN, int MODE>
__global__ __launch_bounds__(256) void k_fc(const float* __restrict__ X,
                                            const float* __restrict__ W,
                                            const float* __restrict__ b,
                                            const float* __restrict__ st,
                                            const float* __restrict__ gamma,
                                            const float* __restrict__ beta,
                                            float* __restrict__ Y) {
  __shared__ float sx[KIN];
  int g = blockIdx.x;
  int c = threadIdx.x;
  for (int k = c; k < KIN; k += 256) {
    float v = X[(long)g * KIN + k];
    if constexpr (MODE == 2) {
      float m = st[k] * (1.f / GGv);
      float var = st[KIN + k] * (1.f / GGv) - m * m;
      v = fmaxf((v - m) * rsqrtf(var + 1e-5f) * gamma[k] + beta[k], 0.f);
    }
    sx[k] = v;
  }
  __syncthreads();
  float acc = b[c];
#pragma unroll 8
  for (int k = 0; k < KIN; k++) acc += sx[k] * W[(long)k * 256 + c];
  Y[(long)g * 256 + c] = (MODE == 0) ? fmaxf(acc, 0.f) : acc;
}

__global__ __launch_bounds__(256) void k_out(const float* __restrict__ X,
                                             const float* __restrict__ st,
                                             const float* __restrict__ gamma,
                                             const float* __restrict__ beta,
                                             const float* __restrict__ Wout,
                                             const float* __restrict__ bout,
                                             float* __restrict__ out) {
  int g = blockIdx.x * 4 + (threadIdx.x >> 6);
  int l = threadIdx.x & 63;
  float a0 = 0.f, a1 = 0.f;
  for (int k = l; k < LBv; k += 64) {
    float z = X[(long)g * LBv + k];
    float m = st[k] * (1.f / GGv);
    float var = st[LBv + k] * (1.f / GGv) - m * m;
    float x = fmaxf((z - m) * rsqrtf(var + 1e-5f) * gamma[k] + beta[k], 0.f);
    a0 += x * Wout[2 * k];
    a1 += x * Wout[2 * k + 1];
  }
  for (int off = 32; off > 0; off >>= 1) {
    a0 += __shfl_down(a0, off);
    a1 += __shfl_down(a1, off);
  }
  if (l == 0) {
    out[2 * g] = a0 + bout[0];
    out[2 * g + 1] = a1 + bout[1];
  }
}

// ---------------- launch ----------------

extern "C" void kernel_launch(void* const* d_in, const int* in_sizes, int n_in,
                              void* d_out, int out_size, void* d_ws, size_t ws_size,
                              hipStream_t stream) {
  const float* x = (const float*)d_in[0];
  const int* ei = (const int*)d_in[1];
  const int* batch = (const int*)d_in[2];
  const float* W0 = (const float*)d_in[4];
  const float* b0 = (const float*)d_in[5];
  const float* Wg = (const float*)d_in[6];
  const float* bg = (const float*)d_in[7];
  const float* gamma_g = (const float*)d_in[8];
  const float* beta_g = (const float*)d_in[9];
  const float* Wl0 = (const float*)d_in[10];
  const float* bl0 = (const float*)d_in[11];
  const float* Wl = (const float*)d_in[12];
  const float* bl = (const float*)d_in[13];
  const float* gamma_l = (const float*)d_in[14];
  const float* beta_l = (const float*)d_in[15];
  const float* Wout = (const float*)d_in[16];
  const float* bout = (const float*)d_in[17];
  float* out = (float*)d_out;

  char* w = (char*)d_ws;
  auto alloc = [&](size_t bytes) {
    void* p = (void*)w;
    w += (bytes + 255) & ~(size_t)255;
    return p;
  };
  // zero-initialized span: bcnt | stAll | ghist | gcur
  int* bcnt = (int*)alloc((size_t)NB * 4);
  float* stAll = (float*)alloc((size_t)(4 * 256 + 2 * 512) * 4);
  int* ghist = (int*)alloc((size_t)64 * 4);
  int* gcur = (int*)alloc((size_t)64 * 4);
  size_t zspan = (char*)w - (char*)bcnt;
  // rest
  uint* bkt = (uint*)alloc((size_t)NB * BCAP * 4);
  int* offs = (int*)alloc((size_t)(NN + 1) * 4);
  int* col = (int*)alloc((size_t)(EE + NB * 2048 + 8192) * 4);
  float* dinv = (float*)alloc((size_t)(NN + 1) * 4);
  int* deg = (int*)alloc((size_t)NN * 4);
  int* perm = (int*)alloc((size_t)NN * 4);
  ushort* u = (ushort*)alloc((size_t)(NN + 1) * DINv * 2);
  ushort* g1 = (ushort*)alloc((size_t)(NN + 1) * GBv * 2);
  ushort* g2 = (ushort*)alloc((size_t)(NN + 1) * GBv * 2);
  ushort* Wt0 = (ushort*)alloc((size_t)DINv * GBv * 2);
  ushort* Wtg = (ushort*)alloc((size_t)GDv * GBv * GBv * 2);
  float* hp = (float*)alloc((size_t)GGv * GBv * 4);
  float* m1 = (float*)alloc((size_t)GGv * LBv * 4);
  float* m2 = (float*)alloc((size_t)GGv * LBv * 4);

  float* stg = stAll;
  float* sth0 = stAll + 4 * 256;
  float* sth1 = sth0 + 512;

  hipMemsetAsync(bcnt, 0, zspan, stream);

  k_bucket<<<NBT, 256, 0, stream>>>(ei, bcnt, bkt);
  k_csr<<<NB, 256, 0, stream>>>(bkt, bcnt, offs, dinv, col, deg, ghist);
  k_dperm<<<NB, 256, 0, stream>>>(deg, ghist, gcur, perm);
  k_prep<<<(UPN + CONVN + ZEXT + 255) / 256, 256, 0, stream>>>(x, dinv, W0, Wg, u, Wt0,
                                                               Wtg, g1, g2);

  // layer 0: agg(u) @ W0 + b0; epilogue writes relu(y)*dinv -> g1 (so layer 1 is MODE0)
  k_layer<64, 0, false, true><<<NTILES, 512, 0, stream>>>(
      u, col, offs, deg, dinv, perm, nullptr, nullptr, nullptr, Wt0, b0, nullptr, g1);
  // layer 1: pure-sum gather of g1 -> agg @ Wg0 + bg0 -> g2 (raw), stats -> stg[0]
  k_layer<128, 0, true, false><<<NTILES, 512, 0, stream>>>(
      g1, col, offs, deg, dinv, perm, nullptr, nullptr, nullptr, Wtg, bg, stg, g2);
  // layers 2..4: BN+relu fold on input, ping-pong g2/g1
  for (int i = 1; i < GDv; i++) {
    const ushort* gin = (i & 1) ? g2 : g1;
    ushort* gout = (i & 1) ? g1 : g2;
    k_layer<128, 2, true, false><<<NTILES, 512, 0, stream>>>(
        gin, col, offs, deg, dinv, perm, stg + (size_t)(i - 1) * 256,
        gamma_g + (size_t)(i - 1) * GBv, beta_g + (size_t)(i - 1) * GBv,
        Wtg + (size_t)i * GBv * GBv, bg + (size_t)i * GBv, stg + (size_t)i * 256, gout);
  }
  // final layer output is g1 (i=3 writes g1)

  // pool with final BN+relu fused
  k_pool2<<<GGv, 128, 0, stream>>>(g1, stg + 3 * 256, gamma_g + 3 * GBv, beta_g + 3 * GBv,
                                   batch, hp);

  // head
  k_fc<GBv, 0><<<GGv, 256, 0, stream>>>(hp, Wl0, bl0, nullptr, nullptr, nullptr, m1);
  k_fc<LBv, 1><<<GGv, 256, 0, stream>>>(m1, Wl, bl, nullptr, nullptr, nullptr, m2);
  k_colstats<<<256, LBv, 0, stream>>>(m2, GGv, sth0);
  k_fc<LBv, 2><<<GGv, 256, 0, stream>>>(m2, Wl + (size_t)LBv * LBv, bl + LBv, sth0,
                                        gamma_l, beta_l, m1);
  k_colstats<<<256, LBv, 0, stream>>>(m1, GGv, sth1);
  k_out<<<GGv / 4, 256, 0, stream>>>(m1, sth1, gamma_l + LBv, beta_l + LBv, Wout, bout, out);
}